// Round 16
// baseline (349.277 us; speedup 1.0000x reference)
//
#include <hip/hip_runtime.h>
#include <hip/hip_bf16.h>

#define GN_EPS 1e-5f

// NOTE: node ids packed as (src<<16)|bf16(weight) in csr_ew; requires n < 65536.

typedef __attribute__((ext_vector_type(8))) short short8;
typedef __attribute__((ext_vector_type(4))) float f32x4;

__device__ __forceinline__ unsigned short f2bf(float f) {
    unsigned u = __float_as_uint(f);
    u += 0x7fffu + ((u >> 16) & 1u);   // round-to-nearest-even
    return (unsigned short)(u >> 16);
}
__device__ __forceinline__ float bflo(unsigned u) { return __uint_as_float(u << 16); }
__device__ __forceinline__ float bfhi(unsigned u) { return __uint_as_float(u & 0xffff0000u); }

// ---------------- CSR build ----------------
__global__ void k_degi(const int* __restrict__ dst, int* __restrict__ degi,
                       unsigned short* __restrict__ slot, int e) {
    int i = blockIdx.x * blockDim.x + threadIdx.x;
    if (i < e) slot[i] = (unsigned short)atomicAdd(&degi[dst[i]], 1);
}

#define SCAN_CHUNK 4096
__global__ __launch_bounds__(256) void k_blocksum(const int* __restrict__ degi,
                                                  int* __restrict__ partial, int n) {
    int base = blockIdx.x * SCAN_CHUNK + threadIdx.x * 16;
    int s = 0;
    #pragma unroll
    for (int q = 0; q < 16; ++q) {
        int i = base + q;
        if (i < n) s += degi[i];
    }
    #pragma unroll
    for (int off = 32; off; off >>= 1) s += __shfl_down(s, off);
    __shared__ int ws[4];
    if ((threadIdx.x & 63) == 0) ws[threadIdx.x >> 6] = s;
    __syncthreads();
    if (threadIdx.x == 0) partial[blockIdx.x] = ws[0] + ws[1] + ws[2] + ws[3];
}

// block b: base = sum(partial[0..b-1]) computed locally (nb <= 13, L2-resident)
__global__ __launch_bounds__(256) void k_scanfinal(const int* __restrict__ degi,
                                                   const int* __restrict__ partial,
                                                   int* __restrict__ rowptr,
                                                   float* __restrict__ dinv, int n, int nb) {
    int blockbase = 0;
    for (int i = 0; i < (int)blockIdx.x; ++i) blockbase += partial[i];

    int base = blockIdx.x * SCAN_CHUNK + threadIdx.x * 16;
    int v[16];
    int s = 0;
    #pragma unroll
    for (int q = 0; q < 16; ++q) {
        int i = base + q;
        v[q] = (i < n) ? degi[i] : 0;
        s += v[q];
    }
    const int lane = threadIdx.x & 63;
    const int wid = threadIdx.x >> 6;
    int x = s;
    #pragma unroll
    for (int off = 1; off < 64; off <<= 1) {
        int t = __shfl_up(x, off);
        if (lane >= off) x += t;
    }
    __shared__ int ws[4];
    if (lane == 63) ws[wid] = x;
    __syncthreads();
    int waveoff = 0;
    if (wid > 0) waveoff += ws[0];
    if (wid > 1) waveoff += ws[1];
    if (wid > 2) waveoff += ws[2];
    int excl = x - s + waveoff + blockbase;
    #pragma unroll
    for (int q = 0; q < 16; ++q) {
        int i = base + q;
        if (i < n) {
            rowptr[i] = excl;
            dinv[i] = rsqrtf((float)(v[q] + 1));
        }
        excl += v[q];
    }
    if ((int)blockIdx.x == nb - 1 && threadIdx.x == 255) {
        rowptr[n] = excl;
    }
}

// XCD-partitioned fill: grid = 8*FILL_CHUNKS; block b scans chunk b>>3 and
// writes only edges whose dst falls in node-range (b&7) -> each csr_ew line is
// dirtied by one XCD only (blockIdx%8 ~ XCD round-robin), killing cross-XCD
// line ping-pong on the random 4B stores.
#define FILL_CHUNKS 256
__global__ __launch_bounds__(256) void k_fill(const int* __restrict__ src,
                                              const int* __restrict__ dst,
                                              const unsigned short* __restrict__ slot,
                                              const int* __restrict__ rowptr,
                                              const float* __restrict__ dinv,
                                              unsigned* __restrict__ csr_ew,
                                              int e, int nseg) {
    int r = blockIdx.x & 7;
    int chunk = blockIdx.x >> 3;
    int per = (e + FILL_CHUNKS - 1) / FILL_CHUNKS;
    int lo = chunk * per;
    int hi = lo + per; if (hi > e) hi = e;
    for (int i = lo + threadIdx.x; i < hi; i += 256) {
        int d = dst[i];
        if (d / nseg == r) {
            int s = src[i];
            float w = dinv[s] * dinv[d];
            csr_ew[rowptr[d] + (int)slot[i]] = ((unsigned)s << 16) | (unsigned)f2bf(w);
        }
    }
}

// ---------------- W prep (all 3 in one launch): Wt[c][k] = bf16(W[k][c]) ----------------
__global__ __launch_bounds__(256) void k_prepW3(const float* __restrict__ W1,
                                                const float* __restrict__ W2,
                                                const float* __restrict__ W3,
                                                unsigned short* __restrict__ Wt) {
    const float* W = blockIdx.x == 0 ? W1 : (blockIdx.x == 1 ? W2 : W3);
    unsigned short* o = Wt + blockIdx.x * 16384;
    __shared__ unsigned short sT[128 * 130];
    const float4* W4 = (const float4*)W;
    for (int idx = threadIdx.x; idx < 128 * 32; idx += 256) {
        int k = idx >> 5, c4 = idx & 31;
        float4 v = W4[k * 32 + c4];
        sT[(c4 * 4 + 0) * 130 + k] = f2bf(v.x);
        sT[(c4 * 4 + 1) * 130 + k] = f2bf(v.y);
        sT[(c4 * 4 + 2) * 130 + k] = f2bf(v.z);
        sT[(c4 * 4 + 3) * 130 + k] = f2bf(v.w);
    }
    __syncthreads();
    for (int idx = threadIdx.x; idx < 128 * 128; idx += 256) {
        int c = idx >> 7, k = idx & 127;
        o[idx] = sT[c * 130 + k];
    }
}

// ---------------- MFMA GEMM (fp32 input, layer 1) ----------------
#define LDK 136
__global__ __launch_bounds__(256) void k_gemm_f32(const float* __restrict__ X,
                                                  const unsigned short* __restrict__ Wt,
                                                  unsigned short* __restrict__ Y,
                                                  int nrows) {
    __shared__ __align__(16) unsigned short sX[64 * LDK];
    __shared__ __align__(16) unsigned short sB[128 * LDK];
    const int t = threadIdx.x;
    const int row0 = blockIdx.x * 64;

    for (int idx = t; idx < 128 * 16; idx += 256) {
        int c = idx >> 4, ch = idx & 15;
        uint4 v = ((const uint4*)(Wt + c * 128))[ch];
        *(uint4*)(&sB[c * LDK + ch * 8]) = v;
    }
    for (int idx = t; idx < 64 * 32; idx += 256) {
        int r = idx >> 5, c4 = idx & 31;
        int grow = row0 + r;
        float4 v = make_float4(0.f, 0.f, 0.f, 0.f);
        if (grow < nrows) v = ((const float4*)(X + (size_t)grow * 128))[c4];
        ushort4 o;
        o.x = f2bf(v.x); o.y = f2bf(v.y); o.z = f2bf(v.z); o.w = f2bf(v.w);
        *(ushort4*)(&sX[r * LDK + c4 * 4]) = o;
    }
    __syncthreads();

    const int w = t >> 6;
    const int lane = t & 63;
    const int m = lane & 15;
    const int quad = lane >> 4;

    f32x4 acc[8] = {};
    #pragma unroll
    for (int ks = 0; ks < 4; ++ks) {
        int ko = ks * 32 + quad * 8;
        short8 a = *(const short8*)(&sX[(w * 16 + m) * LDK + ko]);
        #pragma unroll
        for (int ct = 0; ct < 8; ++ct) {
            short8 b = *(const short8*)(&sB[(ct * 16 + m) * LDK + ko]);
            acc[ct] = __builtin_amdgcn_mfma_f32_16x16x32_bf16(a, b, acc[ct], 0, 0, 0);
        }
    }
    #pragma unroll
    for (int r = 0; r < 4; ++r) {
        int grow = row0 + w * 16 + quad * 4 + r;
        if (grow >= nrows) continue;
        unsigned short* yr = Y + (size_t)grow * 128 + m;
        #pragma unroll
        for (int ct = 0; ct < 8; ++ct) yr[ct * 16] = f2bf(acc[ct][r]);
    }
}

// ---------------- MFMA GEMM (bf16 input + fused GraphNorm affine + ReLU) ----------------
__global__ __launch_bounds__(256) void k_gemm_bf(const unsigned short* __restrict__ Xb,
                                                 const unsigned short* __restrict__ Wt,
                                                 unsigned short* __restrict__ Y,
                                                 const float* __restrict__ cs,
                                                 const float* __restrict__ cb,
                                                 int nrows) {
    __shared__ __align__(16) unsigned short sX[64 * LDK];
    __shared__ __align__(16) unsigned short sB[128 * LDK];
    const int t = threadIdx.x;
    const int row0 = blockIdx.x * 64;

    for (int idx = t; idx < 128 * 16; idx += 256) {
        int c = idx >> 4, ch = idx & 15;
        uint4 v = ((const uint4*)(Wt + c * 128))[ch];
        *(uint4*)(&sB[c * LDK + ch * 8]) = v;
    }
    for (int idx = t; idx < 64 * 32; idx += 256) {
        int r = idx >> 5, c4 = idx & 31;
        int grow = row0 + r;
        uint2 u = make_uint2(0u, 0u);
        if (grow < nrows) u = *(const uint2*)(Xb + (size_t)grow * 128 + c4 * 4);
        float4 s4 = ((const float4*)cs)[c4];
        float4 b4 = ((const float4*)cb)[c4];
        ushort4 o;
        o.x = f2bf(fmaxf(fmaf(bflo(u.x), s4.x, b4.x), 0.f));
        o.y = f2bf(fmaxf(fmaf(bfhi(u.x), s4.y, b4.y), 0.f));
        o.z = f2bf(fmaxf(fmaf(bflo(u.y), s4.z, b4.z), 0.f));
        o.w = f2bf(fmaxf(fmaf(bfhi(u.y), s4.w, b4.w), 0.f));
        *(ushort4*)(&sX[r * LDK + c4 * 4]) = o;
    }
    __syncthreads();

    const int w = t >> 6;
    const int lane = t & 63;
    const int m = lane & 15;
    const int quad = lane >> 4;

    f32x4 acc[8] = {};
    #pragma unroll
    for (int ks = 0; ks < 4; ++ks) {
        int ko = ks * 32 + quad * 8;
        short8 a = *(const short8*)(&sX[(w * 16 + m) * LDK + ko]);
        #pragma unroll
        for (int ct = 0; ct < 8; ++ct) {
            short8 b = *(const short8*)(&sB[(ct * 16 + m) * LDK + ko]);
            acc[ct] = __builtin_amdgcn_mfma_f32_16x16x32_bf16(a, b, acc[ct], 0, 0, 0);
        }
    }
    #pragma unroll
    for (int r = 0; r < 4; ++r) {
        int grow = row0 + w * 16 + quad * 4 + r;
        if (grow >= nrows) continue;
        unsigned short* yr = Y + (size_t)grow * 128 + m;
        #pragma unroll
        for (int ct = 0; ct < 8; ++ct) yr[ct * 16] = f2bf(acc[ct][r]);
    }
}

// ---------------- pull-gather conv: quarter-wave rows (4 rows / VMEM instr) ----------------
__global__ __launch_bounds__(256) void k_gather(const unsigned short* __restrict__ H,
                                                unsigned short* __restrict__ O,
                                                const int* __restrict__ rowptr,
                                                const unsigned* __restrict__ csr_ew,
                                                const float* __restrict__ dinv,
                                                const float* __restrict__ bias, int n) {
    int node = blockIdx.x * 4 + (threadIdx.x >> 6);
    if (node >= n) return;
    int lane = threadIdx.x & 63;
    int qw = lane >> 4;
    int ql = lane & 15;
    const uint4* Hx = (const uint4*)H;
    float di = dinv[node];
    float acc[8] = {};
    if (qw == 0) {
        uint4 u = Hx[(size_t)node * 16 + ql];
        float dd = di * di;
        float4 ba = ((const float4*)bias)[ql * 2];
        float4 bb = ((const float4*)bias)[ql * 2 + 1];
        acc[0] = bflo(u.x) * dd + ba.x; acc[1] = bfhi(u.x) * dd + ba.y;
        acc[2] = bflo(u.y) * dd + ba.z; acc[3] = bfhi(u.y) * dd + ba.w;
        acc[4] = bflo(u.z) * dd + bb.x; acc[5] = bfhi(u.z) * dd + bb.y;
        acc[6] = bflo(u.w) * dd + bb.z; acc[7] = bfhi(u.w) * dd + bb.w;
    }
    int j = rowptr[node];
    const int end = rowptr[node + 1];
    for (; j + 15 < end; j += 16) {
        unsigned ew[4];
        #pragma unroll
        for (int q = 0; q < 4; ++q) ew[q] = csr_ew[j + 4 * q + qw];
        uint4 u[4];
        #pragma unroll
        for (int q = 0; q < 4; ++q) u[q] = Hx[(size_t)(ew[q] >> 16) * 16 + ql];
        #pragma unroll
        for (int q = 0; q < 4; ++q) {
            float nr = __uint_as_float(ew[q] << 16);
            acc[0] += bflo(u[q].x) * nr; acc[1] += bfhi(u[q].x) * nr;
            acc[2] += bflo(u[q].y) * nr; acc[3] += bfhi(u[q].y) * nr;
            acc[4] += bflo(u[q].z) * nr; acc[5] += bfhi(u[q].z) * nr;
            acc[6] += bflo(u[q].w) * nr; acc[7] += bfhi(u[q].w) * nr;
        }
    }
    for (int jj = j + qw; jj < end; jj += 4) {
        unsigned ew = csr_ew[jj];
        uint4 u = Hx[(size_t)(ew >> 16) * 16 + ql];
        float nr = __uint_as_float(ew << 16);
        acc[0] += bflo(u.x) * nr; acc[1] += bfhi(u.x) * nr;
        acc[2] += bflo(u.y) * nr; acc[3] += bfhi(u.y) * nr;
        acc[4] += bflo(u.z) * nr; acc[5] += bfhi(u.z) * nr;
        acc[6] += bflo(u.w) * nr; acc[7] += bfhi(u.w) * nr;
    }
    #pragma unroll
    for (int i = 0; i < 8; ++i) {
        acc[i] += __shfl_down(acc[i], 32);
        acc[i] += __shfl_down(acc[i], 16);
    }
    if (qw == 0) {
        uint4 o;
        o.x = (unsigned)f2bf(acc[0]) | ((unsigned)f2bf(acc[1]) << 16);
        o.y = (unsigned)f2bf(acc[2]) | ((unsigned)f2bf(acc[3]) << 16);
        o.z = (unsigned)f2bf(acc[4]) | ((unsigned)f2bf(acc[5]) << 16);
        o.w = (unsigned)f2bf(acc[6]) | ((unsigned)f2bf(acc[7]) << 16);
        *(uint4*)(O + (size_t)node * 128 + ql * 8) = o;
    }
}

// ---------------- layer-3 gather with fused output projection ----------------
__global__ __launch_bounds__(256) void k_gatherproj(const unsigned short* __restrict__ H,
                                                    const int* __restrict__ rowptr,
                                                    const unsigned* __restrict__ csr_ew,
                                                    const float* __restrict__ dinv,
                                                    const float* __restrict__ bias,
                                                    const float* __restrict__ Wo,
                                                    const float* __restrict__ bo,
                                                    float* __restrict__ out, int n) {
    int node = blockIdx.x * 4 + (threadIdx.x >> 6);
    if (node >= n) return;
    int lane = threadIdx.x & 63;
    int qw = lane >> 4;
    int ql = lane & 15;
    const uint4* Hx = (const uint4*)H;
    float di = dinv[node];
    float acc[8] = {};
    if (qw == 0) {
        uint4 u = Hx[(size_t)node * 16 + ql];
        float dd = di * di;
        float4 ba = ((const float4*)bias)[ql * 2];
        float4 bb = ((const float4*)bias)[ql * 2 + 1];
        acc[0] = bflo(u.x) * dd + ba.x; acc[1] = bfhi(u.x) * dd + ba.y;
        acc[2] = bflo(u.y) * dd + ba.z; acc[3] = bfhi(u.y) * dd + ba.w;
        acc[4] = bflo(u.z) * dd + bb.x; acc[5] = bfhi(u.z) * dd + bb.y;
        acc[6] = bflo(u.w) * dd + bb.z; acc[7] = bfhi(u.w) * dd + bb.w;
    }
    int j = rowptr[node];
    const int end = rowptr[node + 1];
    for (; j + 15 < end; j += 16) {
        unsigned ew[4];
        #pragma unroll
        for (int q = 0; q < 4; ++q) ew[q] = csr_ew[j + 4 * q + qw];
        uint4 u[4];
        #pragma unroll
        for (int q = 0; q < 4; ++q) u[q] = Hx[(size_t)(ew[q] >> 16) * 16 + ql];
        #pragma unroll
        for (int q = 0; q < 4; ++q) {
            float nr = __uint_as_float(ew[q] << 16);
            acc[0] += bflo(u[q].x) * nr; acc[1] += bfhi(u[q].x) * nr;
            acc[2] += bflo(u[q].y) * nr; acc[3] += bfhi(u[q].y) * nr;
            acc[4] += bflo(u[q].z) * nr; acc[5] += bfhi(u[q].z) * nr;
            acc[6] += bflo(u[q].w) * nr; acc[7] += bfhi(u[q].w) * nr;
        }
    }
    for (int jj = j + qw; jj < end; jj += 4) {
        unsigned ew = csr_ew[jj];
        uint4 u = Hx[(size_t)(ew >> 16) * 16 + ql];
        float nr = __uint_as_float(ew << 16);
        acc[0] += bflo(u.x) * nr; acc[1] += bfhi(u.x) * nr;
        acc[2] += bflo(u.y) * nr; acc[3] += bfhi(u.y) * nr;
        acc[4] += bflo(u.z) * nr; acc[5] += bfhi(u.z) * nr;
        acc[6] += bflo(u.w) * nr; acc[7] += bfhi(u.w) * nr;
    }
    #pragma unroll
    for (int i = 0; i < 8; ++i) {
        acc[i] += __shfl_down(acc[i], 32);
        acc[i] += __shfl_down(acc[i], 16);
    }
    float p0 = 0.f, p1 = 0.f;
    #pragma unroll
    for (int i = 0; i < 8; ++i) {
        p0 += acc[i] * Wo[(ql * 8 + i) * 2];
        p1 += acc[i] * Wo[(ql * 8 + i) * 2 + 1];
    }
    #pragma unroll
    for (int off = 8; off; off >>= 1) {
        p0 += __shfl_down(p0, off);
        p1 += __shfl_down(p1, off);
    }
    if (lane == 0) {
        out[(size_t)node * 2]     = p0 + bo[0];
        out[(size_t)node * 2 + 1] = p1 + bo[1];
    }
}

// ---------------- GraphNorm stats on bf16 buffer ----------------
#define STAT_NB 256
__global__ __launch_bounds__(256) void k_stats(const unsigned short* __restrict__ H,
                                               float* __restrict__ pS,
                                               float* __restrict__ pQ, int n) {
    const uint4* H4 = (const uint4*)H;
    const size_t nv = (size_t)n * 16;
    float s[8] = {}, q[8] = {};
    for (size_t f = (size_t)blockIdx.x * 256 + threadIdx.x; f < nv;
         f += (size_t)256 * STAT_NB) {
        uint4 u = H4[f];
        float v;
        v = bflo(u.x); s[0] += v; q[0] += v * v;
        v = bfhi(u.x); s[1] += v; q[1] += v * v;
        v = bflo(u.y); s[2] += v; q[2] += v * v;
        v = bfhi(u.y); s[3] += v; q[3] += v * v;
        v = bflo(u.z); s[4] += v; q[4] += v * v;
        v = bfhi(u.z); s[5] += v; q[5] += v * v;
        v = bflo(u.w); s[6] += v; q[6] += v * v;
        v = bfhi(u.w); s[7] += v; q[7] += v * v;
    }
    __shared__ float ls[256][9], lq[256][9];
    int t = threadIdx.x;
    #pragma unroll
    for (int i = 0; i < 8; ++i) { ls[t][i] = s[i]; lq[t][i] = q[i]; }
    __syncthreads();
    #pragma unroll
    for (int off = 128; off >= 16; off >>= 1) {
        if (t < off) {
            #pragma unroll
            for (int i = 0; i < 8; ++i) { ls[t][i] += ls[t + off][i]; lq[t][i] += lq[t + off][i]; }
        }
        __syncthreads();
    }
    if (t < 16) {
        #pragma unroll
        for (int i = 0; i < 8; ++i) {
            pS[(size_t)blockIdx.x * 128 + t * 8 + i] = ls[t][i];
            pQ[(size_t)blockIdx.x * 128 + t * 8 + i] = lq[t][i];
        }
    }
}

__global__ void k_finstats(const float* __restrict__ pS, const float* __restrict__ pQ,
                           const float* __restrict__ w, const float* __restrict__ b,
                           const float* __restrict__ alpha,
                           float* __restrict__ colscale, float* __restrict__ colshift,
                           int n) {
    int c = threadIdx.x;
    if (c >= 128) return;
    float s = 0.f, q = 0.f;
    #pragma unroll 8
    for (int blk = 0; blk < STAT_NB; ++blk) {
        s += pS[blk * 128 + c];
        q += pQ[blk * 128 + c];
    }
    float inv_n = 1.0f / (float)n;
    float m = s * inv_n;
    float eh2 = q * inv_n;
    float a = alpha[c];
    float var = eh2 - (2.0f * a - a * a) * m * m;
    float scale = rsqrtf(var + GN_EPS) * w[c];
    colscale[c] = scale;
    colshift[c] = b[c] - a * m * scale;
}

extern "C" void kernel_launch(void* const* d_in, const int* in_sizes, int n_in,
                              void* d_out, int out_size, void* d_ws, size_t ws_size,
                              hipStream_t stream) {
    const float* x    = (const float*)d_in[0];
    const int*   ei   = (const int*)  d_in[1];
    const float* W1   = (const float*)d_in[2];
    const float* b1   = (const float*)d_in[3];
    const float* W2   = (const float*)d_in[4];
    const float* b2   = (const float*)d_in[5];
    const float* W3   = (const float*)d_in[6];
    const float* b3   = (const float*)d_in[7];
    const float* gn1w = (const float*)d_in[8];
    const float* gn1b = (const float*)d_in[9];
    const float* gn1a = (const float*)d_in[10];
    const float* gn2w = (const float*)d_in[11];
    const float* gn2b = (const float*)d_in[12];
    const float* gn2a = (const float*)d_in[13];
    const float* Wout = (const float*)d_in[14];
    const float* bout = (const float*)d_in[15];
    float* out = (float*)d_out;

    const int n = in_sizes[0] / 128;
    const int e = in_sizes[1] / 2;
    const int* srcI = ei;
    const int* dstI = ei + e;

    unsigned short* bufH = (unsigned short*)d_ws;                     // n*128 bf16 (gemm out)
    unsigned short* bufG = bufH + (size_t)n * 128;                    // n*128 bf16 (gather out)
    unsigned short* slot = bufH;             // aliases bufH (dead until gemm1), e ushorts
    float* dinv     = (float*)(bufG + (size_t)n * 128);               // n
    float* colscale = dinv + n;                                       // 128
    float* colshift = colscale + 128;                                 // 128
    int*   degi     = (int*)(colshift + 128);                         // n  (memset region)
    int*   rowptr   = degi + n;                                       // n+1
    int*   partial  = rowptr + n + 1;                                 // 64
    float* pS       = (float*)(partial + 64);                         // STAT_NB*128
    float* pQ       = pS + STAT_NB * 128;                             // STAT_NB*128
    unsigned* csr_ew = (unsigned*)(pQ + STAT_NB * 128);               // e uints
    unsigned short* Wt = (unsigned short*)(csr_ew + e);               // 3*16384

    const int nb = (n + SCAN_CHUNK - 1) / SCAN_CHUNK;
    const int nseg = (n + 7) / 8;

    // ---- CSR build + W prep ----
    hipMemsetAsync(degi, 0, (size_t)n * sizeof(int), stream);
    k_degi<<<(e + 255) / 256, 256, 0, stream>>>(dstI, degi, slot, e);
    k_blocksum<<<nb, 256, 0, stream>>>(degi, partial, n);
    k_scanfinal<<<nb, 256, 0, stream>>>(degi, partial, rowptr, dinv, n, nb);
    k_fill<<<FILL_CHUNKS * 8, 256, 0, stream>>>(srcI, dstI, slot, rowptr, dinv, csr_ew, e, nseg);
    k_prepW3<<<3, 256, 0, stream>>>(W1, W2, W3, Wt);

    const int gemmGrid = (n + 63) / 64;
    const int gathGrid = (n + 3) / 4;

    // layer 1
    k_gemm_f32<<<gemmGrid, 256, 0, stream>>>(x, Wt, bufH, n);
    k_gather<<<gathGrid, 256, 0, stream>>>(bufH, bufG, rowptr, csr_ew, dinv, b1, n);
    k_stats<<<STAT_NB, 256, 0, stream>>>(bufG, pS, pQ, n);
    k_finstats<<<1, 128, 0, stream>>>(pS, pQ, gn1w, gn1b, gn1a, colscale, colshift, n);

    // layer 2
    k_gemm_bf<<<gemmGrid, 256, 0, stream>>>(bufG, Wt + 16384, bufH, colscale, colshift, n);
    k_gather<<<gathGrid, 256, 0, stream>>>(bufH, bufG, rowptr, csr_ew, dinv, b2, n);
    k_stats<<<STAT_NB, 256, 0, stream>>>(bufG, pS, pQ, n);
    k_finstats<<<1, 128, 0, stream>>>(pS, pQ, gn2w, gn2b, gn2a, colscale, colshift, n);

    // layer 3 + fused projection
    k_gemm_bf<<<gemmGrid, 256, 0, stream>>>(bufG, Wt + 32768, bufH, colscale, colshift, n);
    k_gatherproj<<<gathGrid, 256, 0, stream>>>(bufH, rowptr, csr_ew, dinv, b3, Wout, bout, out, n);
}

// Round 17
// 318.966 us; speedup vs baseline: 1.0950x; 1.0950x over previous
//
#include <hip/hip_runtime.h>
#include <hip/hip_bf16.h>

#define GN_EPS 1e-5f

// NOTE: node ids packed as (src<<16)|bf16(weight) in csr_ew; requires n < 65536.

typedef __attribute__((ext_vector_type(8))) short short8;
typedef __attribute__((ext_vector_type(4))) float f32x4;

__device__ __forceinline__ unsigned short f2bf(float f) {
    unsigned u = __float_as_uint(f);
    u += 0x7fffu + ((u >> 16) & 1u);   // round-to-nearest-even
    return (unsigned short)(u >> 16);
}
__device__ __forceinline__ float bflo(unsigned u) { return __uint_as_float(u << 16); }
__device__ __forceinline__ float bfhi(unsigned u) { return __uint_as_float(u & 0xffff0000u); }

// ---------------- CSR build ----------------
__global__ void k_degi(const int* __restrict__ dst, int* __restrict__ degi,
                       unsigned short* __restrict__ slot, int e) {
    int i = blockIdx.x * blockDim.x + threadIdx.x;
    if (i < e) slot[i] = (unsigned short)atomicAdd(&degi[dst[i]], 1);
}

#define SCAN_CHUNK 4096
__global__ __launch_bounds__(256) void k_blocksum(const int* __restrict__ degi,
                                                  int* __restrict__ partial, int n) {
    int base = blockIdx.x * SCAN_CHUNK + threadIdx.x * 16;
    int s = 0;
    #pragma unroll
    for (int q = 0; q < 16; ++q) {
        int i = base + q;
        if (i < n) s += degi[i];
    }
    #pragma unroll
    for (int off = 32; off; off >>= 1) s += __shfl_down(s, off);
    __shared__ int ws[4];
    if ((threadIdx.x & 63) == 0) ws[threadIdx.x >> 6] = s;
    __syncthreads();
    if (threadIdx.x == 0) partial[blockIdx.x] = ws[0] + ws[1] + ws[2] + ws[3];
}

// block b: base = sum(partial[0..b-1]) computed locally (nb <= 13, L2-resident)
__global__ __launch_bounds__(256) void k_scanfinal(const int* __restrict__ degi,
                                                   const int* __restrict__ partial,
                                                   int* __restrict__ rowptr,
                                                   float* __restrict__ dinv, int n, int nb) {
    int blockbase = 0;
    for (int i = 0; i < (int)blockIdx.x; ++i) blockbase += partial[i];

    int base = blockIdx.x * SCAN_CHUNK + threadIdx.x * 16;
    int v[16];
    int s = 0;
    #pragma unroll
    for (int q = 0; q < 16; ++q) {
        int i = base + q;
        v[q] = (i < n) ? degi[i] : 0;
        s += v[q];
    }
    const int lane = threadIdx.x & 63;
    const int wid = threadIdx.x >> 6;
    int x = s;
    #pragma unroll
    for (int off = 1; off < 64; off <<= 1) {
        int t = __shfl_up(x, off);
        if (lane >= off) x += t;
    }
    __shared__ int ws[4];
    if (lane == 63) ws[wid] = x;
    __syncthreads();
    int waveoff = 0;
    if (wid > 0) waveoff += ws[0];
    if (wid > 1) waveoff += ws[1];
    if (wid > 2) waveoff += ws[2];
    int excl = x - s + waveoff + blockbase;
    #pragma unroll
    for (int q = 0; q < 16; ++q) {
        int i = base + q;
        if (i < n) {
            rowptr[i] = excl;
            dinv[i] = rsqrtf((float)(v[q] + 1));
        }
        excl += v[q];
    }
    if ((int)blockIdx.x == nb - 1 && threadIdx.x == 255) {
        rowptr[n] = excl;
    }
}

// fill with packed (src, bf16 weight) entries; weight = dinv[src]*dinv[dst]
__global__ void k_fill(const int* __restrict__ src, const int* __restrict__ dst,
                       const unsigned short* __restrict__ slot, const int* __restrict__ rowptr,
                       const float* __restrict__ dinv,
                       unsigned* __restrict__ csr_ew, int e) {
    int i = blockIdx.x * blockDim.x + threadIdx.x;
    if (i < e) {
        int s = src[i], d = dst[i];
        float w = dinv[s] * dinv[d];
        csr_ew[rowptr[d] + (int)slot[i]] = ((unsigned)s << 16) | (unsigned)f2bf(w);
    }
}

// ---------------- W prep (W1, W2): Wt[c][k] = bf16(W[k][c]) ----------------
__global__ __launch_bounds__(256) void k_prepW2(const float* __restrict__ W1,
                                                const float* __restrict__ W2,
                                                unsigned short* __restrict__ Wt) {
    const float* W = blockIdx.x == 0 ? W1 : W2;
    unsigned short* o = Wt + blockIdx.x * 16384;
    __shared__ unsigned short sT[128 * 130];
    const float4* W4 = (const float4*)W;
    for (int idx = threadIdx.x; idx < 128 * 32; idx += 256) {
        int k = idx >> 5, c4 = idx & 31;
        float4 v = W4[k * 32 + c4];
        sT[(c4 * 4 + 0) * 130 + k] = f2bf(v.x);
        sT[(c4 * 4 + 1) * 130 + k] = f2bf(v.y);
        sT[(c4 * 4 + 2) * 130 + k] = f2bf(v.z);
        sT[(c4 * 4 + 3) * 130 + k] = f2bf(v.w);
    }
    __syncthreads();
    for (int idx = threadIdx.x; idx < 128 * 128; idx += 256) {
        int c = idx >> 7, k = idx & 127;
        o[idx] = sT[c * 130 + k];
    }
}

// ---------------- M = W3 @ Wout (128x2), mb = b3^T @ Wout + bout ----------------
__global__ __launch_bounds__(128) void k_prepM(const float* __restrict__ W3,
                                               const float* __restrict__ Wo,
                                               const float* __restrict__ b3,
                                               const float* __restrict__ bo,
                                               float* __restrict__ M,
                                               float* __restrict__ mb) {
    int k = threadIdx.x;
    float m0 = 0.f, m1 = 0.f;
    for (int c = 0; c < 128; ++c) {
        float w = W3[k * 128 + c];
        m0 += w * Wo[c * 2];
        m1 += w * Wo[c * 2 + 1];
    }
    M[k * 2] = m0;
    M[k * 2 + 1] = m1;
    if (k < 2) {
        float s = 0.f;
        for (int c = 0; c < 128; ++c) s += b3[c] * Wo[c * 2 + k];
        mb[k] = s + bo[k];
    }
}

// ---------------- MFMA GEMM (fp32 input, layer 1) ----------------
#define LDK 136
__global__ __launch_bounds__(256) void k_gemm_f32(const float* __restrict__ X,
                                                  const unsigned short* __restrict__ Wt,
                                                  unsigned short* __restrict__ Y,
                                                  int nrows) {
    __shared__ __align__(16) unsigned short sX[64 * LDK];
    __shared__ __align__(16) unsigned short sB[128 * LDK];
    const int t = threadIdx.x;
    const int row0 = blockIdx.x * 64;

    for (int idx = t; idx < 128 * 16; idx += 256) {
        int c = idx >> 4, ch = idx & 15;
        uint4 v = ((const uint4*)(Wt + c * 128))[ch];
        *(uint4*)(&sB[c * LDK + ch * 8]) = v;
    }
    for (int idx = t; idx < 64 * 32; idx += 256) {
        int r = idx >> 5, c4 = idx & 31;
        int grow = row0 + r;
        float4 v = make_float4(0.f, 0.f, 0.f, 0.f);
        if (grow < nrows) v = ((const float4*)(X + (size_t)grow * 128))[c4];
        ushort4 o;
        o.x = f2bf(v.x); o.y = f2bf(v.y); o.z = f2bf(v.z); o.w = f2bf(v.w);
        *(ushort4*)(&sX[r * LDK + c4 * 4]) = o;
    }
    __syncthreads();

    const int w = t >> 6;
    const int lane = t & 63;
    const int m = lane & 15;
    const int quad = lane >> 4;

    f32x4 acc[8] = {};
    #pragma unroll
    for (int ks = 0; ks < 4; ++ks) {
        int ko = ks * 32 + quad * 8;
        short8 a = *(const short8*)(&sX[(w * 16 + m) * LDK + ko]);
        #pragma unroll
        for (int ct = 0; ct < 8; ++ct) {
            short8 b = *(const short8*)(&sB[(ct * 16 + m) * LDK + ko]);
            acc[ct] = __builtin_amdgcn_mfma_f32_16x16x32_bf16(a, b, acc[ct], 0, 0, 0);
        }
    }
    #pragma unroll
    for (int r = 0; r < 4; ++r) {
        int grow = row0 + w * 16 + quad * 4 + r;
        if (grow >= nrows) continue;
        unsigned short* yr = Y + (size_t)grow * 128 + m;
        #pragma unroll
        for (int ct = 0; ct < 8; ++ct) yr[ct * 16] = f2bf(acc[ct][r]);
    }
}

// ---------------- MFMA GEMM (bf16 input + fused GraphNorm affine + ReLU) ----------------
__global__ __launch_bounds__(256) void k_gemm_bf(const unsigned short* __restrict__ Xb,
                                                 const unsigned short* __restrict__ Wt,
                                                 unsigned short* __restrict__ Y,
                                                 const float* __restrict__ cs,
                                                 const float* __restrict__ cb,
                                                 int nrows) {
    __shared__ __align__(16) unsigned short sX[64 * LDK];
    __shared__ __align__(16) unsigned short sB[128 * LDK];
    const int t = threadIdx.x;
    const int row0 = blockIdx.x * 64;

    for (int idx = t; idx < 128 * 16; idx += 256) {
        int c = idx >> 4, ch = idx & 15;
        uint4 v = ((const uint4*)(Wt + c * 128))[ch];
        *(uint4*)(&sB[c * LDK + ch * 8]) = v;
    }
    for (int idx = t; idx < 64 * 32; idx += 256) {
        int r = idx >> 5, c4 = idx & 31;
        int grow = row0 + r;
        uint2 u = make_uint2(0u, 0u);
        if (grow < nrows) u = *(const uint2*)(Xb + (size_t)grow * 128 + c4 * 4);
        float4 s4 = ((const float4*)cs)[c4];
        float4 b4 = ((const float4*)cb)[c4];
        ushort4 o;
        o.x = f2bf(fmaxf(fmaf(bflo(u.x), s4.x, b4.x), 0.f));
        o.y = f2bf(fmaxf(fmaf(bfhi(u.x), s4.y, b4.y), 0.f));
        o.z = f2bf(fmaxf(fmaf(bflo(u.y), s4.z, b4.z), 0.f));
        o.w = f2bf(fmaxf(fmaf(bfhi(u.y), s4.w, b4.w), 0.f));
        *(ushort4*)(&sX[r * LDK + c4 * 4]) = o;
    }
    __syncthreads();

    const int w = t >> 6;
    const int lane = t & 63;
    const int m = lane & 15;
    const int quad = lane >> 4;

    f32x4 acc[8] = {};
    #pragma unroll
    for (int ks = 0; ks < 4; ++ks) {
        int ko = ks * 32 + quad * 8;
        short8 a = *(const short8*)(&sX[(w * 16 + m) * LDK + ko]);
        #pragma unroll
        for (int ct = 0; ct < 8; ++ct) {
            short8 b = *(const short8*)(&sB[(ct * 16 + m) * LDK + ko]);
            acc[ct] = __builtin_amdgcn_mfma_f32_16x16x32_bf16(a, b, acc[ct], 0, 0, 0);
        }
    }
    #pragma unroll
    for (int r = 0; r < 4; ++r) {
        int grow = row0 + w * 16 + quad * 4 + r;
        if (grow >= nrows) continue;
        unsigned short* yr = Y + (size_t)grow * 128 + m;
        #pragma unroll
        for (int ct = 0; ct < 8; ++ct) yr[ct * 16] = f2bf(acc[ct][r]);
    }
}

// ---------------- pull-gather conv: quarter-wave rows (4 rows / VMEM instr) ----------------
__global__ __launch_bounds__(256) void k_gather(const unsigned short* __restrict__ H,
                                                unsigned short* __restrict__ O,
                                                const int* __restrict__ rowptr,
                                                const unsigned* __restrict__ csr_ew,
                                                const float* __restrict__ dinv,
                                                const float* __restrict__ bias, int n) {
    int node = blockIdx.x * 4 + (threadIdx.x >> 6);
    if (node >= n) return;
    int lane = threadIdx.x & 63;
    int qw = lane >> 4;
    int ql = lane & 15;
    const uint4* Hx = (const uint4*)H;
    float di = dinv[node];
    float acc[8] = {};
    if (qw == 0) {
        uint4 u = Hx[(size_t)node * 16 + ql];
        float dd = di * di;
        float4 ba = ((const float4*)bias)[ql * 2];
        float4 bb = ((const float4*)bias)[ql * 2 + 1];
        acc[0] = bflo(u.x) * dd + ba.x; acc[1] = bfhi(u.x) * dd + ba.y;
        acc[2] = bflo(u.y) * dd + ba.z; acc[3] = bfhi(u.y) * dd + ba.w;
        acc[4] = bflo(u.z) * dd + bb.x; acc[5] = bfhi(u.z) * dd + bb.y;
        acc[6] = bflo(u.w) * dd + bb.z; acc[7] = bfhi(u.w) * dd + bb.w;
    }
    int j = rowptr[node];
    const int end = rowptr[node + 1];
    for (; j + 15 < end; j += 16) {
        unsigned ew[4];
        #pragma unroll
        for (int q = 0; q < 4; ++q) ew[q] = csr_ew[j + 4 * q + qw];
        uint4 u[4];
        #pragma unroll
        for (int q = 0; q < 4; ++q) u[q] = Hx[(size_t)(ew[q] >> 16) * 16 + ql];
        #pragma unroll
        for (int q = 0; q < 4; ++q) {
            float nr = __uint_as_float(ew[q] << 16);
            acc[0] += bflo(u[q].x) * nr; acc[1] += bfhi(u[q].x) * nr;
            acc[2] += bflo(u[q].y) * nr; acc[3] += bfhi(u[q].y) * nr;
            acc[4] += bflo(u[q].z) * nr; acc[5] += bfhi(u[q].z) * nr;
            acc[6] += bflo(u[q].w) * nr; acc[7] += bfhi(u[q].w) * nr;
        }
    }
    for (int jj = j + qw; jj < end; jj += 4) {
        unsigned ew = csr_ew[jj];
        uint4 u = Hx[(size_t)(ew >> 16) * 16 + ql];
        float nr = __uint_as_float(ew << 16);
        acc[0] += bflo(u.x) * nr; acc[1] += bfhi(u.x) * nr;
        acc[2] += bflo(u.y) * nr; acc[3] += bfhi(u.y) * nr;
        acc[4] += bflo(u.z) * nr; acc[5] += bfhi(u.z) * nr;
        acc[6] += bflo(u.w) * nr; acc[7] += bfhi(u.w) * nr;
    }
    #pragma unroll
    for (int i = 0; i < 8; ++i) {
        acc[i] += __shfl_down(acc[i], 32);
        acc[i] += __shfl_down(acc[i], 16);
    }
    if (qw == 0) {
        uint4 o;
        o.x = (unsigned)f2bf(acc[0]) | ((unsigned)f2bf(acc[1]) << 16);
        o.y = (unsigned)f2bf(acc[2]) | ((unsigned)f2bf(acc[3]) << 16);
        o.z = (unsigned)f2bf(acc[4]) | ((unsigned)f2bf(acc[5]) << 16);
        o.w = (unsigned)f2bf(acc[6]) | ((unsigned)f2bf(acc[7]) << 16);
        *(uint4*)(O + (size_t)node * 128 + ql * 8) = o;
    }
}

// ---------------- Z = relu(affine(bufG)) @ M  (n x 2, fp32) ----------------
__global__ __launch_bounds__(256) void k_zproj(const unsigned short* __restrict__ Xb,
                                               const float* __restrict__ M,
                                               const float* __restrict__ cs,
                                               const float* __restrict__ cb,
                                               float2* __restrict__ Z, int n) {
    int node = blockIdx.x * 4 + (threadIdx.x >> 6);
    if (node >= n) return;
    int lane = threadIdx.x & 63;   // cols 2*lane, 2*lane+1
    unsigned u = ((const unsigned*)Xb)[(size_t)node * 64 + lane];
    int c0 = lane * 2;
    float a = fmaxf(fmaf(bflo(u), cs[c0], cb[c0]), 0.f);
    float b = fmaxf(fmaf(bfhi(u), cs[c0 + 1], cb[c0 + 1]), 0.f);
    float p0 = a * M[c0 * 2]     + b * M[(c0 + 1) * 2];
    float p1 = a * M[c0 * 2 + 1] + b * M[(c0 + 1) * 2 + 1];
    #pragma unroll
    for (int off = 32; off; off >>= 1) {
        p0 += __shfl_down(p0, off);
        p1 += __shfl_down(p1, off);
    }
    if (lane == 0) Z[node] = make_float2(p0, p1);
}

// ---------------- final: out[i] = dinv[i]^2*Z[i] + sum w*Z[s] + mb ----------------
// 16-lane group per node (4 groups/wave, 4 waves/block -> 16 nodes/block)
__global__ __launch_bounds__(256) void k_gatherZ(const float2* __restrict__ Z,
                                                 const int* __restrict__ rowptr,
                                                 const unsigned* __restrict__ csr_ew,
                                                 const float* __restrict__ dinv,
                                                 const float* __restrict__ mb,
                                                 float* __restrict__ out, int n) {
    int wid = threadIdx.x >> 6;
    int lane = threadIdx.x & 63;
    int g = lane >> 4;
    int gl = lane & 15;
    int node = blockIdx.x * 16 + wid * 4 + g;
    if (node >= n) return;
    float2 acc = make_float2(0.f, 0.f);
    if (gl == 0) {
        float di = dinv[node];
        float2 z = Z[node];
        acc.x = z.x * di * di + mb[0];
        acc.y = z.y * di * di + mb[1];
    }
    int j = rowptr[node];
    const int end = rowptr[node + 1];
    for (int jj = j + gl; jj < end; jj += 16) {
        unsigned ew = csr_ew[jj];
        float2 z = Z[ew >> 16];
        float w = __uint_as_float(ew << 16);
        acc.x += z.x * w;
        acc.y += z.y * w;
    }
    #pragma unroll
    for (int off = 8; off; off >>= 1) {
        acc.x += __shfl_down(acc.x, off);
        acc.y += __shfl_down(acc.y, off);
    }
    if (gl == 0) {
        out[(size_t)node * 2]     = acc.x;
        out[(size_t)node * 2 + 1] = acc.y;
    }
}

// ---------------- GraphNorm stats on bf16 buffer ----------------
#define STAT_NB 256
__global__ __launch_bounds__(256) void k_stats(const unsigned short* __restrict__ H,
                                               float* __restrict__ pS,
                                               float* __restrict__ pQ, int n) {
    const uint4* H4 = (const uint4*)H;
    const size_t nv = (size_t)n * 16;
    float s[8] = {}, q[8] = {};
    for (size_t f = (size_t)blockIdx.x * 256 + threadIdx.x; f < nv;
         f += (size_t)256 * STAT_NB) {
        uint4 u = H4[f];
        float v;
        v = bflo(u.x); s[0] += v; q[0] += v * v;
        v = bfhi(u.x); s[1] += v; q[1] += v * v;
        v = bflo(u.y); s[2] += v; q[2] += v * v;
        v = bfhi(u.y); s[3] += v; q[3] += v * v;
        v = bflo(u.z); s[4] += v; q[4] += v * v;
        v = bfhi(u.z); s[5] += v; q[5] += v * v;
        v = bflo(u.w); s[6] += v; q[6] += v * v;
        v = bfhi(u.w); s[7] += v; q[7] += v * v;
    }
    __shared__ float ls[256][9], lq[256][9];
    int t = threadIdx.x;
    #pragma unroll
    for (int i = 0; i < 8; ++i) { ls[t][i] = s[i]; lq[t][i] = q[i]; }
    __syncthreads();
    #pragma unroll
    for (int off = 128; off >= 16; off >>= 1) {
        if (t < off) {
            #pragma unroll
            for (int i = 0; i < 8; ++i) { ls[t][i] += ls[t + off][i]; lq[t][i] += lq[t + off][i]; }
        }
        __syncthreads();
    }
    if (t < 16) {
        #pragma unroll
        for (int i = 0; i < 8; ++i) {
            pS[(size_t)blockIdx.x * 128 + t * 8 + i] = ls[t][i];
            pQ[(size_t)blockIdx.x * 128 + t * 8 + i] = lq[t][i];
        }
    }
}

__global__ void k_finstats(const float* __restrict__ pS, const float* __restrict__ pQ,
                           const float* __restrict__ w, const float* __restrict__ b,
                           const float* __restrict__ alpha,
                           float* __restrict__ colscale, float* __restrict__ colshift,
                           int n) {
    int c = threadIdx.x;
    if (c >= 128) return;
    float s = 0.f, q = 0.f;
    #pragma unroll 8
    for (int blk = 0; blk < STAT_NB; ++blk) {
        s += pS[blk * 128 + c];
        q += pQ[blk * 128 + c];
    }
    float inv_n = 1.0f / (float)n;
    float m = s * inv_n;
    float eh2 = q * inv_n;
    float a = alpha[c];
    float var = eh2 - (2.0f * a - a * a) * m * m;
    float scale = rsqrtf(var + GN_EPS) * w[c];
    colscale[c] = scale;
    colshift[c] = b[c] - a * m * scale;
}

extern "C" void kernel_launch(void* const* d_in, const int* in_sizes, int n_in,
                              void* d_out, int out_size, void* d_ws, size_t ws_size,
                              hipStream_t stream) {
    const float* x    = (const float*)d_in[0];
    const int*   ei   = (const int*)  d_in[1];
    const float* W1   = (const float*)d_in[2];
    const float* b1   = (const float*)d_in[3];
    const float* W2   = (const float*)d_in[4];
    const float* b2   = (const float*)d_in[5];
    const float* W3   = (const float*)d_in[6];
    const float* b3   = (const float*)d_in[7];
    const float* gn1w = (const float*)d_in[8];
    const float* gn1b = (const float*)d_in[9];
    const float* gn1a = (const float*)d_in[10];
    const float* gn2w = (const float*)d_in[11];
    const float* gn2b = (const float*)d_in[12];
    const float* gn2a = (const float*)d_in[13];
    const float* Wout = (const float*)d_in[14];
    const float* bout = (const float*)d_in[15];
    float* out = (float*)d_out;

    const int n = in_sizes[0] / 128;
    const int e = in_sizes[1] / 2;
    const int* srcI = ei;
    const int* dstI = ei + e;

    unsigned short* bufH = (unsigned short*)d_ws;                     // n*128 bf16 (gemm out)
    unsigned short* bufG = bufH + (size_t)n * 128;                    // n*128 bf16 (gather out)
    unsigned short* slot = bufH;             // aliases bufH (dead until gemm1), e ushorts
    float* dinv     = (float*)(bufG + (size_t)n * 128);               // n
    float* colscale = dinv + n;                                       // 128
    float* colshift = colscale + 128;                                 // 128
    int*   degi     = (int*)(colshift + 128);                         // n  (memset region)
    int*   rowptr   = degi + n;                                       // n+1
    int*   partial  = rowptr + n + 1;                                 // 64
    float* pS       = (float*)(partial + 64);                         // STAT_NB*128
    float* pQ       = pS + STAT_NB * 128;                             // STAT_NB*128
    unsigned* csr_ew = (unsigned*)(pQ + STAT_NB * 128);               // e uints
    unsigned short* Wt = (unsigned short*)(csr_ew + e);               // 2*16384
    float* M        = (float*)(Wt + 2 * 16384);                       // 256
    float* mb       = M + 256;                                        // 2
    float2* Z       = (float2*)(mb + 2);                              // n float2

    const int nb = (n + SCAN_CHUNK - 1) / SCAN_CHUNK;

    // ---- CSR build + weight prep ----
    hipMemsetAsync(degi, 0, (size_t)n * sizeof(int), stream);
    k_degi<<<(e + 255) / 256, 256, 0, stream>>>(dstI, degi, slot, e);
    k_blocksum<<<nb, 256, 0, stream>>>(degi, partial, n);
    k_scanfinal<<<nb, 256, 0, stream>>>(degi, partial, rowptr, dinv, n, nb);
    k_fill<<<(e + 255) / 256, 256, 0, stream>>>(srcI, dstI, slot, rowptr, dinv, csr_ew, e);
    k_prepW2<<<2, 256, 0, stream>>>(W1, W2, Wt);
    k_prepM<<<1, 128, 0, stream>>>(W3, Wout, b3, bout, M, mb);

    const int gemmGrid = (n + 63) / 64;
    const int gathGrid = (n + 3) / 4;

    // layer 1
    k_gemm_f32<<<gemmGrid, 256, 0, stream>>>(x, Wt, bufH, n);
    k_gather<<<gathGrid, 256, 0, stream>>>(bufH, bufG, rowptr, csr_ew, dinv, b1, n);
    k_stats<<<STAT_NB, 256, 0, stream>>>(bufG, pS, pQ, n);
    k_finstats<<<1, 128, 0, stream>>>(pS, pQ, gn1w, gn1b, gn1a, colscale, colshift, n);

    // layer 2
    k_gemm_bf<<<gemmGrid, 256, 0, stream>>>(bufG, Wt + 16384, bufH, colscale, colshift, n);
    k_gather<<<gathGrid, 256, 0, stream>>>(bufH, bufG, rowptr, csr_ew, dinv, b2, n);
    k_stats<<<STAT_NB, 256, 0, stream>>>(bufG, pS, pQ, n);
    k_finstats<<<1, 128, 0, stream>>>(pS, pQ, gn2w, gn2b, gn2a, colscale, colshift, n);

    // layer 3 collapsed: Z = relu(affine(bufG)) @ (W3@Wout); out = A_hat * Z + mb
    k_zproj<<<gathGrid, 256, 0, stream>>>(bufG, M, colscale, colshift, Z, n);
    k_gatherZ<<<(n + 15) / 16, 256, 0, stream>>>(Z, rowptr, csr_ew, dinv, mb, out, n);
}